// Round 7
// baseline (1558.953 us; speedup 1.0000x reference)
//
#include <hip/hip_runtime.h>
#include <hip/hip_bf16.h>

// GestureCNNLSTM: conv1(1->16,3x3,p1)+relu+pool2 -> conv2(16->32,3x3,p1)+relu+pool2
//  -> flatten 192 -> gx GEMM (+b_ih+b_hh) -> 512-step LSTM (H=256) -> 64-dim classifier.
// x [128][512][13][10] f32, out [128][64] f32. feat/gx f16 in ws (159.4 MB).
//
// LSTM weight residency (per gate row, 128 f16 pairs): 36 pairs LDS (144 KB)
// + 40 pairs ArchVGPR (80 regs) + 52 pairs AGPR via inline-asm accvgpr
// (104 a-regs/thread; unified gfx950 file, 2 waves/SIMD => 256-reg cap).
// Zero weight streaming per step (R5 was L2-request-rate-bound at 208 KB/step).

typedef _Float16 half2v __attribute__((ext_vector_type(2)));
typedef _Float16 f16x8 __attribute__((ext_vector_type(8)));
typedef float f32x4 __attribute__((ext_vector_type(4)));

__device__ __forceinline__ float dot2f16(half2v a, half2v b, float c) {
#if defined(__has_builtin)
#if __has_builtin(__builtin_amdgcn_fdot2)
    return __builtin_amdgcn_fdot2(a, b, c, false);
#else
    return c + (float)a.x * (float)b.x + (float)a.y * (float)b.y;
#endif
#else
    return c + (float)a.x * (float)b.x + (float)a.y * (float)b.y;
#endif
}

__device__ __forceinline__ unsigned int packf2(const float* p) {
    half2v hv;
    hv.x = (_Float16)p[0];
    hv.y = (_Float16)p[1];
    return __builtin_bit_cast(unsigned int, hv);
}

__device__ __forceinline__ half2v bch2(unsigned int u) {
    return __builtin_bit_cast(half2v, u);
}

__device__ __forceinline__ uint4 pack8(const float* p) {
    uint4 v;
    v.x = packf2(p + 0);
    v.y = packf2(p + 2);
    v.z = packf2(p + 4);
    v.w = packf2(p + 6);
    return v;
}

// ---------------- Kernel A: fused conv1+pool1+conv2+pool2 ----------------
__global__ __launch_bounds__(256) void conv_kernel(
    const float* __restrict__ x,     // [65536][13][10]
    const float* __restrict__ c1w,   // [16][1][3][3]
    const float* __restrict__ c1b,   // [16]
    const float* __restrict__ c2w,   // [32][16][3][3]
    const float* __restrict__ c2b,   // [32]
    _Float16* __restrict__ feat)     // [65536][192]
{
    __shared__ float w1t[9 * 16];
    __shared__ float b1s[16];
    __shared__ float w2t[16 * 9 * 32];
    __shared__ float b2s[32];
    __shared__ float xp[4][14 * 12];
    __shared__ float p1p[4][16 * 8 * 7];

    const int tid = threadIdx.x;

    for (int idx = tid; idx < 144; idx += 256) {
        int oc = idx / 9, k = idx % 9;
        w1t[k * 16 + oc] = c1w[idx];
    }
    if (tid < 16) b1s[tid] = c1b[tid];
    for (int idx = tid; idx < 4608; idx += 256) {
        int oc = idx / 144, ic = (idx / 9) % 16, k = idx % 9;
        w2t[(ic * 9 + k) * 32 + oc] = c2w[idx];
    }
    if (tid < 32) b2s[tid] = c2b[tid];

    const int w = tid >> 6;
    const int lane = tid & 63;
    const int img = blockIdx.x * 4 + w;

    for (int i = lane; i < 14 * 12; i += 64) xp[w][i] = 0.f;
    for (int i = lane; i < 16 * 8 * 7; i += 64) p1p[w][i] = 0.f;
    __syncthreads();

    const float* xin = x + (size_t)img * 130;
    for (int i = lane; i < 130; i += 64) {
        int r = i / 10, c = i % 10;
        xp[w][(r + 1) * 12 + (c + 1)] = xin[i];
    }
    __syncthreads();

    {
        const int oc = lane & 15, q = lane >> 4;
        #pragma unroll
        for (int i = 0; i < 8; i++) {
            int pos = i * 4 + q;
            if (pos < 30) {
                int ph = pos / 5, pw = pos % 5;
                float cmax = -1e30f;
                #pragma unroll
                for (int pt = 0; pt < 4; pt++) {
                    int Y = 2 * ph + (pt >> 1), X = 2 * pw + (pt & 1);
                    float s = 0.f;
                    #pragma unroll
                    for (int k = 0; k < 9; k++) {
                        int dy = k / 3, dx = k % 3;
                        s += w1t[k * 16 + oc] * xp[w][(Y + dy) * 12 + X + dx];
                    }
                    cmax = fmaxf(cmax, s);
                }
                p1p[w][(oc * 8 + ph + 1) * 7 + (pw + 1)] = fmaxf(0.f, cmax + b1s[oc]);
            }
        }
    }
    __syncthreads();

    {
        const int oc = lane & 31, pw2 = lane >> 5;
        float acc[3][4];
        #pragma unroll
        for (int a = 0; a < 3; a++)
            #pragma unroll
            for (int b = 0; b < 4; b++) acc[a][b] = 0.f;

        for (int ic = 0; ic < 16; ic++) {
            #pragma unroll
            for (int k = 0; k < 9; k++) {
                int dy = k / 3, dx = k % 3;
                float wv = w2t[(ic * 9 + k) * 32 + oc];
                #pragma unroll
                for (int ph2 = 0; ph2 < 3; ph2++) {
                    #pragma unroll
                    for (int pt = 0; pt < 4; pt++) {
                        int y = 2 * ph2 + (pt >> 1) + dy;
                        int xx = 2 * pw2 + (pt & 1) + dx;
                        acc[ph2][pt] += wv * p1p[w][(ic * 8 + y) * 7 + xx];
                    }
                }
            }
        }
        float bias = b2s[oc];
        _Float16* fo = feat + (size_t)img * 192;
        #pragma unroll
        for (int ph2 = 0; ph2 < 3; ph2++) {
            float m = fmaxf(fmaxf(acc[ph2][0], acc[ph2][1]),
                            fmaxf(acc[ph2][2], acc[ph2][3]));
            fo[oc * 6 + ph2 * 2 + pw2] = (_Float16)fmaxf(0.f, m + bias);
        }
    }
}

// ---------------- Kernel B: gx = feat @ W_ih^T + bias via MFMA f16 ----------
__global__ __launch_bounds__(256) void gemm_gx_kernel(
    const _Float16* __restrict__ feat,  // [65536][192]
    const float* __restrict__ Wih,      // [1024][192]
    const float* __restrict__ bih,
    const float* __restrict__ bhh,
    _Float16* __restrict__ gx)          // [65536][1024]
{
    __shared__ uint4 As4[64][25];   // 25.6 KB, row stride 400 B
    __shared__ uint4 Bs4[64][25];   // 25.6 KB

    const int tid = threadIdx.x;
    const int n0 = blockIdx.x * 64;
    const int m0 = blockIdx.y * 64;

    #pragma unroll
    for (int it = 0; it < 6; it++) {
        int q = tid + it * 256;
        int m = q / 24, c = q % 24;
        As4[m][c] = *(const uint4*)(feat + (size_t)(m0 + m) * 192 + c * 8);
    }
    unsigned int* Bu = (unsigned int*)Bs4;
    #pragma unroll
    for (int it = 0; it < 24; it++) {
        int q = tid + it * 256;
        int n = q / 96, p = q % 96;
        Bu[n * 100 + p] = packf2(Wih + (size_t)(n0 + n) * 192 + 2 * p);
    }
    __syncthreads();

    const int wv = tid >> 6;
    const int lane = tid & 63;
    const int lm = lane & 15;
    const int lk = lane >> 4;

    f32x4 acc[4] = {{0.f, 0.f, 0.f, 0.f}, {0.f, 0.f, 0.f, 0.f},
                    {0.f, 0.f, 0.f, 0.f}, {0.f, 0.f, 0.f, 0.f}};

    #pragma unroll
    for (int ks = 0; ks < 6; ks++) {
        f16x8 a = __builtin_bit_cast(f16x8, As4[wv * 16 + lm][ks * 4 + lk]);
        #pragma unroll
        for (int j = 0; j < 4; j++) {
            f16x8 b = __builtin_bit_cast(f16x8, Bs4[j * 16 + lm][ks * 4 + lk]);
            acc[j] = __builtin_amdgcn_mfma_f32_16x16x32_f16(a, b, acc[j], 0, 0, 0);
        }
    }

    #pragma unroll
    for (int j = 0; j < 4; j++) {
        int n = n0 + j * 16 + lm;
        float bias = bih[n] + bhh[n];
        #pragma unroll
        for (int i = 0; i < 4; i++) {
            int m = m0 + wv * 16 + lk * 4 + i;
            gx[(size_t)m * 1024 + n] = (_Float16)(acc[j][i] + bias);
        }
    }
}

// ---------------- Kernel C: 512-step LSTM + classifier ----------------
// 128 blocks x 512 threads (8 waves, 2/SIMD). Thread t owns rows r0=t, r1=t+512.
// Per row: pairs 0..35 LDS | 36..75 ArchVGPR | 76..127 AGPR (inline asm).
// AGPR reads are asm volatile so they are NOT LICM-hoisted (which would
// re-materialize 104 VGPR copies and spill — the R2/R3 failure mode).
#define AGPR_W(var, val) asm volatile("v_accvgpr_write_b32 %0, %1" : "=a"(var) : "v"(val))
#define AGPR_R(var, dst) asm volatile("v_accvgpr_read_b32 %0, %1" : "=v"(dst) : "a"(var))

#define REP52(M) M(0) M(1) M(2) M(3) M(4) M(5) M(6) M(7) M(8) M(9) M(10) M(11) \
    M(12) M(13) M(14) M(15) M(16) M(17) M(18) M(19) M(20) M(21) M(22) M(23) \
    M(24) M(25) M(26) M(27) M(28) M(29) M(30) M(31) M(32) M(33) M(34) M(35) \
    M(36) M(37) M(38) M(39) M(40) M(41) M(42) M(43) M(44) M(45) M(46) M(47) \
    M(48) M(49) M(50) M(51)

#define DECLA(i) unsigned int agA##i, agB##i;
#define INITA(i) { AGPR_W(agA##i, packf2(w0 + 152 + 2 * (i))); \
                   AGPR_W(agB##i, packf2(w1 + 152 + 2 * (i))); }

#define ASTEP(c, i0, i1, i2, i3) { \
    uint4 hv = hb4[19 + (c)]; unsigned int u_; \
    AGPR_R(agA##i0, u_); acc0 = dot2f16(bch2(u_), bch2(hv.x), acc0); \
    AGPR_R(agB##i0, u_); acc1 = dot2f16(bch2(u_), bch2(hv.x), acc1); \
    AGPR_R(agA##i1, u_); acc0 = dot2f16(bch2(u_), bch2(hv.y), acc0); \
    AGPR_R(agB##i1, u_); acc1 = dot2f16(bch2(u_), bch2(hv.y), acc1); \
    AGPR_R(agA##i2, u_); acc0 = dot2f16(bch2(u_), bch2(hv.z), acc0); \
    AGPR_R(agB##i2, u_); acc1 = dot2f16(bch2(u_), bch2(hv.z), acc1); \
    AGPR_R(agA##i3, u_); acc0 = dot2f16(bch2(u_), bch2(hv.w), acc0); \
    AGPR_R(agB##i3, u_); acc1 = dot2f16(bch2(u_), bch2(hv.w), acc1); }

__global__ __launch_bounds__(512, 2) void lstm_kernel(
    const _Float16* __restrict__ gx, // [128][512][1024]
    const float* __restrict__ Whh,   // [1024][256]
    const float* __restrict__ clsw,  // [64][256]
    const float* __restrict__ clsb,  // [64]
    float* __restrict__ out)         // [128][64]
{
    __shared__ uint4 wl4[9][1024];                     // 144 KB: pairs 0..35
    __shared__ __align__(16) _Float16 hbuf[2][256];    // 1 KB
    __shared__ float xg[512];                          // 2 KB

    const int t = threadIdx.x;
    const int b = blockIdx.x;
    const int r0 = t, r1 = t + 512;

    const float* w0 = Whh + (size_t)r0 * 256;
    const float* w1 = Whh + (size_t)r1 * 256;

    // LDS weights: pairs 0..35 (f32 elems 0..71)
    #pragma unroll
    for (int ch = 0; ch < 9; ch++) {
        wl4[ch][r0] = pack8(w0 + 8 * ch);
        wl4[ch][r1] = pack8(w1 + 8 * ch);
    }
    // ArchVGPR weights: pairs 36..75 (f32 elems 72..151)
    half2v wr0[40], wr1[40];
    #pragma unroll
    for (int q = 0; q < 40; q++) {
        wr0[q] = bch2(packf2(w0 + 72 + 2 * q));
        wr1[q] = bch2(packf2(w1 + 72 + 2 * q));
    }
    // AGPR weights: pairs 76..127 (f32 elems 152..255)
    REP52(DECLA)
    REP52(INITA)

    if (t < 256) hbuf[0][t] = (_Float16)0.f;
    __syncthreads();

    float c = 0.f;
    int cur = 0;
    const _Float16* gxb = gx + (size_t)b * 512 * 1024;
    float ga = (float)gxb[r0];
    float gb = (float)gxb[r1];

    for (int step = 0; step < 512; step++) {
        const _Float16* gxn = gxb + (size_t)((step + 1) & 511) * 1024;
        _Float16 na = gxn[r0];
        _Float16 nb = gxn[r1];

        float acc0 = ga, acc1 = gb;
        const uint4* hb4 = (const uint4*)&hbuf[cur][0];  // 32 chunks of 4 pairs

        // AGPR section: h chunks 19..31
        ASTEP(0, 0, 1, 2, 3)
        ASTEP(1, 4, 5, 6, 7)
        ASTEP(2, 8, 9, 10, 11)
        ASTEP(3, 12, 13, 14, 15)
        ASTEP(4, 16, 17, 18, 19)
        ASTEP(5, 20, 21, 22, 23)
        ASTEP(6, 24, 25, 26, 27)
        ASTEP(7, 28, 29, 30, 31)
        ASTEP(8, 32, 33, 34, 35)
        ASTEP(9, 36, 37, 38, 39)
        ASTEP(10, 40, 41, 42, 43)
        ASTEP(11, 44, 45, 46, 47)
        ASTEP(12, 48, 49, 50, 51)

        // LDS section: h chunks 0..8
        #pragma unroll
        for (int ch = 0; ch < 9; ch++) {
            uint4 u0 = wl4[ch][r0];
            uint4 u1 = wl4[ch][r1];
            uint4 hv = hb4[ch];
            acc0 = dot2f16(bch2(u0.x), bch2(hv.x), acc0);
            acc0 = dot2f16(bch2(u0.y), bch2(hv.y), acc0);
            acc0 = dot2f16(bch2(u0.z), bch2(hv.z), acc0);
            acc0 = dot2f16(bch2(u0.w), bch2(hv.w), acc0);
            acc1 = dot2f16(bch2(u1.x), bch2(hv.x), acc1);
            acc1 = dot2f16(bch2(u1.y), bch2(hv.y), acc1);
            acc1 = dot2f16(bch2(u1.z), bch2(hv.z), acc1);
            acc1 = dot2f16(bch2(u1.w), bch2(hv.w), acc1);
        }
        // ArchVGPR section: h chunks 9..18
        #pragma unroll
        for (int cc = 0; cc < 10; cc++) {
            uint4 hv = hb4[9 + cc];
            acc0 = dot2f16(wr0[4 * cc + 0], bch2(hv.x), acc0);
            acc0 = dot2f16(wr0[4 * cc + 1], bch2(hv.y), acc0);
            acc0 = dot2f16(wr0[4 * cc + 2], bch2(hv.z), acc0);
            acc0 = dot2f16(wr0[4 * cc + 3], bch2(hv.w), acc0);
            acc1 = dot2f16(wr1[4 * cc + 0], bch2(hv.x), acc1);
            acc1 = dot2f16(wr1[4 * cc + 1], bch2(hv.y), acc1);
            acc1 = dot2f16(wr1[4 * cc + 2], bch2(hv.z), acc1);
            acc1 = dot2f16(wr1[4 * cc + 3], bch2(hv.w), acc1);
        }

        if (t >= 256) {           // acc0 = f_j, acc1 = o_j for j = t-256
            xg[t - 256] = acc0;
            xg[t] = acc1;
        }
        __syncthreads();
        if (t < 256) {            // acc0 = i_j, acc1 = g_j for j = t
            float i_ = 1.f / (1.f + __expf(-acc0));
            float g_ = 1.f - 2.f / (__expf(2.f * acc1) + 1.f);
            float f_ = 1.f / (1.f + __expf(-xg[t]));
            float o_ = 1.f / (1.f + __expf(-xg[t + 256]));
            c = f_ * c + i_ * g_;
            float th = 1.f - 2.f / (__expf(2.f * c) + 1.f);
            float h = o_ * th;
            hbuf[cur ^ 1][t] = (_Float16)h;
        }
        __syncthreads();
        cur ^= 1;
        ga = (float)na;
        gb = (float)nb;
    }

    if (t < 64) {
        const float* cw = clsw + t * 256;
        float s = clsb[t];
        for (int k = 0; k < 256; k++) s += cw[k] * (float)hbuf[cur][k];
        out[b * 64 + t] = s;
    }
}

extern "C" void kernel_launch(void* const* d_in, const int* in_sizes, int n_in,
                              void* d_out, int out_size, void* d_ws, size_t ws_size,
                              hipStream_t stream) {
    const float* x    = (const float*)d_in[0];
    const float* c1w  = (const float*)d_in[1];
    const float* c1b  = (const float*)d_in[2];
    const float* c2w  = (const float*)d_in[3];
    const float* c2b  = (const float*)d_in[4];
    const float* Wih  = (const float*)d_in[5];
    const float* bih  = (const float*)d_in[6];
    const float* Whh  = (const float*)d_in[7];
    const float* bhh  = (const float*)d_in[8];
    const float* clsw = (const float*)d_in[9];
    const float* clsb = (const float*)d_in[10];

    _Float16* feat = (_Float16*)d_ws;                   // 25.2 MB
    _Float16* gx   = feat + (size_t)65536 * 192;        // 134.2 MB
    float* outp = (float*)d_out;

    hipLaunchKernelGGL(conv_kernel, dim3(16384), dim3(256), 0, stream,
                       x, c1w, c1b, c2w, c2b, feat);
    hipLaunchKernelGGL(gemm_gx_kernel, dim3(16, 1024), dim3(256), 0, stream,
                       feat, Wih, bih, bhh, gx);
    hipLaunchKernelGGL(lstm_kernel, dim3(128), dim3(512), 0, stream,
                       gx, Whh, clsw, clsb, outp);
}

// Round 8
// 1506.446 us; speedup vs baseline: 1.0349x; 1.0349x over previous
//
#include <hip/hip_runtime.h>
#include <hip/hip_bf16.h>

// GestureCNNLSTM: conv1(1->16,3x3,p1)+relu+pool2 -> conv2(16->32,3x3,p1)+relu+pool2
//  -> flatten 192 -> gx GEMM (+b_ih+b_hh) -> 512-step LSTM (H=256) -> 64-dim classifier.
// x [128][512][13][10] f32, out [128][64] f32. feat/gx f16 in ws (159.4 MB).
//
// LSTM weight residency (per gate row, 128 f16 pairs): 36 pairs LDS (144 KB)
// + 40 pairs ArchVGPR (80 regs) + 52 pairs AGPR (104 a-regs; gfx950 unified
// file, 2 waves/SIMD => 256-reg cap). Zero per-step weight streaming.
// R6 lesson: AGPR reads must be BATCHED (8 per asm volatile) — per-read
// volatile asm serializes the whole section (+1250 cyc/step).

typedef _Float16 half2v __attribute__((ext_vector_type(2)));
typedef _Float16 f16x8 __attribute__((ext_vector_type(8)));
typedef float f32x4 __attribute__((ext_vector_type(4)));

__device__ __forceinline__ float dot2f16(half2v a, half2v b, float c) {
#if defined(__has_builtin)
#if __has_builtin(__builtin_amdgcn_fdot2)
    return __builtin_amdgcn_fdot2(a, b, c, false);
#else
    return c + (float)a.x * (float)b.x + (float)a.y * (float)b.y;
#endif
#else
    return c + (float)a.x * (float)b.x + (float)a.y * (float)b.y;
#endif
}

__device__ __forceinline__ unsigned int packf2(const float* p) {
    half2v hv;
    hv.x = (_Float16)p[0];
    hv.y = (_Float16)p[1];
    return __builtin_bit_cast(unsigned int, hv);
}

__device__ __forceinline__ half2v bch2(unsigned int u) {
    return __builtin_bit_cast(half2v, u);
}

__device__ __forceinline__ uint4 pack8(const float* p) {
    uint4 v;
    v.x = packf2(p + 0);
    v.y = packf2(p + 2);
    v.z = packf2(p + 4);
    v.w = packf2(p + 6);
    return v;
}

// ---------------- Kernel A: fused conv1+pool1+conv2+pool2 ----------------
__global__ __launch_bounds__(256) void conv_kernel(
    const float* __restrict__ x,     // [65536][13][10]
    const float* __restrict__ c1w,   // [16][1][3][3]
    const float* __restrict__ c1b,   // [16]
    const float* __restrict__ c2w,   // [32][16][3][3]
    const float* __restrict__ c2b,   // [32]
    _Float16* __restrict__ feat)     // [65536][192]
{
    __shared__ float w1t[9 * 16];
    __shared__ float b1s[16];
    __shared__ float w2t[16 * 9 * 32];
    __shared__ float b2s[32];
    __shared__ float xp[4][14 * 12];
    __shared__ float p1p[4][16 * 8 * 7];

    const int tid = threadIdx.x;

    for (int idx = tid; idx < 144; idx += 256) {
        int oc = idx / 9, k = idx % 9;
        w1t[k * 16 + oc] = c1w[idx];
    }
    if (tid < 16) b1s[tid] = c1b[tid];
    for (int idx = tid; idx < 4608; idx += 256) {
        int oc = idx / 144, ic = (idx / 9) % 16, k = idx % 9;
        w2t[(ic * 9 + k) * 32 + oc] = c2w[idx];
    }
    if (tid < 32) b2s[tid] = c2b[tid];

    const int w = tid >> 6;
    const int lane = tid & 63;
    const int img = blockIdx.x * 4 + w;

    for (int i = lane; i < 14 * 12; i += 64) xp[w][i] = 0.f;
    for (int i = lane; i < 16 * 8 * 7; i += 64) p1p[w][i] = 0.f;
    __syncthreads();

    const float* xin = x + (size_t)img * 130;
    for (int i = lane; i < 130; i += 64) {
        int r = i / 10, c = i % 10;
        xp[w][(r + 1) * 12 + (c + 1)] = xin[i];
    }
    __syncthreads();

    {
        const int oc = lane & 15, q = lane >> 4;
        #pragma unroll
        for (int i = 0; i < 8; i++) {
            int pos = i * 4 + q;
            if (pos < 30) {
                int ph = pos / 5, pw = pos % 5;
                float cmax = -1e30f;
                #pragma unroll
                for (int pt = 0; pt < 4; pt++) {
                    int Y = 2 * ph + (pt >> 1), X = 2 * pw + (pt & 1);
                    float s = 0.f;
                    #pragma unroll
                    for (int k = 0; k < 9; k++) {
                        int dy = k / 3, dx = k % 3;
                        s += w1t[k * 16 + oc] * xp[w][(Y + dy) * 12 + X + dx];
                    }
                    cmax = fmaxf(cmax, s);
                }
                p1p[w][(oc * 8 + ph + 1) * 7 + (pw + 1)] = fmaxf(0.f, cmax + b1s[oc]);
            }
        }
    }
    __syncthreads();

    {
        const int oc = lane & 31, pw2 = lane >> 5;
        float acc[3][4];
        #pragma unroll
        for (int a = 0; a < 3; a++)
            #pragma unroll
            for (int b = 0; b < 4; b++) acc[a][b] = 0.f;

        for (int ic = 0; ic < 16; ic++) {
            #pragma unroll
            for (int k = 0; k < 9; k++) {
                int dy = k / 3, dx = k % 3;
                float wv = w2t[(ic * 9 + k) * 32 + oc];
                #pragma unroll
                for (int ph2 = 0; ph2 < 3; ph2++) {
                    #pragma unroll
                    for (int pt = 0; pt < 4; pt++) {
                        int y = 2 * ph2 + (pt >> 1) + dy;
                        int xx = 2 * pw2 + (pt & 1) + dx;
                        acc[ph2][pt] += wv * p1p[w][(ic * 8 + y) * 7 + xx];
                    }
                }
            }
        }
        float bias = b2s[oc];
        _Float16* fo = feat + (size_t)img * 192;
        #pragma unroll
        for (int ph2 = 0; ph2 < 3; ph2++) {
            float m = fmaxf(fmaxf(acc[ph2][0], acc[ph2][1]),
                            fmaxf(acc[ph2][2], acc[ph2][3]));
            fo[oc * 6 + ph2 * 2 + pw2] = (_Float16)fmaxf(0.f, m + bias);
        }
    }
}

// ---------------- Kernel B: gx = feat @ W_ih^T + bias via MFMA f16 ----------
__global__ __launch_bounds__(256) void gemm_gx_kernel(
    const _Float16* __restrict__ feat,  // [65536][192]
    const float* __restrict__ Wih,      // [1024][192]
    const float* __restrict__ bih,
    const float* __restrict__ bhh,
    _Float16* __restrict__ gx)          // [65536][1024]
{
    __shared__ uint4 As4[64][25];   // 25.6 KB, row stride 400 B
    __shared__ uint4 Bs4[64][25];   // 25.6 KB

    const int tid = threadIdx.x;
    const int n0 = blockIdx.x * 64;
    const int m0 = blockIdx.y * 64;

    #pragma unroll
    for (int it = 0; it < 6; it++) {
        int q = tid + it * 256;
        int m = q / 24, c = q % 24;
        As4[m][c] = *(const uint4*)(feat + (size_t)(m0 + m) * 192 + c * 8);
    }
    unsigned int* Bu = (unsigned int*)Bs4;
    #pragma unroll
    for (int it = 0; it < 24; it++) {
        int q = tid + it * 256;
        int n = q / 96, p = q % 96;
        Bu[n * 100 + p] = packf2(Wih + (size_t)(n0 + n) * 192 + 2 * p);
    }
    __syncthreads();

    const int wv = tid >> 6;
    const int lane = tid & 63;
    const int lm = lane & 15;
    const int lk = lane >> 4;

    f32x4 acc[4] = {{0.f, 0.f, 0.f, 0.f}, {0.f, 0.f, 0.f, 0.f},
                    {0.f, 0.f, 0.f, 0.f}, {0.f, 0.f, 0.f, 0.f}};

    #pragma unroll
    for (int ks = 0; ks < 6; ks++) {
        f16x8 a = __builtin_bit_cast(f16x8, As4[wv * 16 + lm][ks * 4 + lk]);
        #pragma unroll
        for (int j = 0; j < 4; j++) {
            f16x8 b = __builtin_bit_cast(f16x8, Bs4[j * 16 + lm][ks * 4 + lk]);
            acc[j] = __builtin_amdgcn_mfma_f32_16x16x32_f16(a, b, acc[j], 0, 0, 0);
        }
    }

    #pragma unroll
    for (int j = 0; j < 4; j++) {
        int n = n0 + j * 16 + lm;
        float bias = bih[n] + bhh[n];
        #pragma unroll
        for (int i = 0; i < 4; i++) {
            int m = m0 + wv * 16 + lk * 4 + i;
            gx[(size_t)m * 1024 + n] = (_Float16)(acc[j][i] + bias);
        }
    }
}

// ---------------- Kernel C: 512-step LSTM + classifier ----------------
// 128 blocks x 512 threads (8 waves, 2/SIMD). Thread t owns rows r0=t, r1=t+512.
// Per row: pairs 0..35 LDS | 36..75 ArchVGPR | 76..127 AGPR.
// AGPR reads batched 8-per-asm-volatile: the asm blocks order only vs each
// other; the dependent dot2s are C code, so the scheduler interleaves chunk-k
// dots with chunk-(k+1) reads (R6's per-read volatile serialized everything).
#define AGPR_W(var, val) asm volatile("v_accvgpr_write_b32 %0, %1" : "=a"(var) : "v"(val))

#define AGPR_R8(d0,d1,d2,d3,d4,d5,d6,d7, s0,s1,s2,s3,s4,s5,s6,s7) \
    asm volatile( \
        "v_accvgpr_read_b32 %0, %8\n\t" \
        "v_accvgpr_read_b32 %1, %9\n\t" \
        "v_accvgpr_read_b32 %2, %10\n\t" \
        "v_accvgpr_read_b32 %3, %11\n\t" \
        "v_accvgpr_read_b32 %4, %12\n\t" \
        "v_accvgpr_read_b32 %5, %13\n\t" \
        "v_accvgpr_read_b32 %6, %14\n\t" \
        "v_accvgpr_read_b32 %7, %15" \
        : "=v"(d0), "=v"(d1), "=v"(d2), "=v"(d3), \
          "=v"(d4), "=v"(d5), "=v"(d6), "=v"(d7) \
        : "a"(s0), "a"(s1), "a"(s2), "a"(s3), \
          "a"(s4), "a"(s5), "a"(s6), "a"(s7))

#define REP52(M) M(0) M(1) M(2) M(3) M(4) M(5) M(6) M(7) M(8) M(9) M(10) M(11) \
    M(12) M(13) M(14) M(15) M(16) M(17) M(18) M(19) M(20) M(21) M(22) M(23) \
    M(24) M(25) M(26) M(27) M(28) M(29) M(30) M(31) M(32) M(33) M(34) M(35) \
    M(36) M(37) M(38) M(39) M(40) M(41) M(42) M(43) M(44) M(45) M(46) M(47) \
    M(48) M(49) M(50) M(51)

#define DECLA(i) unsigned int agA##i, agB##i;
#define INITA(i) { AGPR_W(agA##i, packf2(w0 + 152 + 2 * (i))); \
                   AGPR_W(agB##i, packf2(w1 + 152 + 2 * (i))); }

#define ASTEP(c, i0, i1, i2, i3) { \
    uint4 hv = hb4[19 + (c)]; \
    unsigned int dA0, dB0, dA1, dB1, dA2, dB2, dA3, dB3; \
    AGPR_R8(dA0, dB0, dA1, dB1, dA2, dB2, dA3, dB3, \
            agA##i0, agB##i0, agA##i1, agB##i1, \
            agA##i2, agB##i2, agA##i3, agB##i3); \
    acc0 = dot2f16(bch2(dA0), bch2(hv.x), acc0); \
    acc1 = dot2f16(bch2(dB0), bch2(hv.x), acc1); \
    acc0 = dot2f16(bch2(dA1), bch2(hv.y), acc0); \
    acc1 = dot2f16(bch2(dB1), bch2(hv.y), acc1); \
    acc0 = dot2f16(bch2(dA2), bch2(hv.z), acc0); \
    acc1 = dot2f16(bch2(dB2), bch2(hv.z), acc1); \
    acc0 = dot2f16(bch2(dA3), bch2(hv.w), acc0); \
    acc1 = dot2f16(bch2(dB3), bch2(hv.w), acc1); }

__global__ __launch_bounds__(512, 2) void lstm_kernel(
    const _Float16* __restrict__ gx, // [128][512][1024]
    const float* __restrict__ Whh,   // [1024][256]
    const float* __restrict__ clsw,  // [64][256]
    const float* __restrict__ clsb,  // [64]
    float* __restrict__ out)         // [128][64]
{
    __shared__ uint4 wl4[9][1024];                     // 144 KB: pairs 0..35
    __shared__ __align__(16) _Float16 hbuf[2][256];    // 1 KB
    __shared__ float xg[512];                          // 2 KB

    const int t = threadIdx.x;
    const int b = blockIdx.x;
    const int r0 = t, r1 = t + 512;

    const float* w0 = Whh + (size_t)r0 * 256;
    const float* w1 = Whh + (size_t)r1 * 256;

    // LDS weights: pairs 0..35 (f32 elems 0..71)
    #pragma unroll
    for (int ch = 0; ch < 9; ch++) {
        wl4[ch][r0] = pack8(w0 + 8 * ch);
        wl4[ch][r1] = pack8(w1 + 8 * ch);
    }
    // ArchVGPR weights: pairs 36..75 (f32 elems 72..151)
    half2v wr0[40], wr1[40];
    #pragma unroll
    for (int q = 0; q < 40; q++) {
        wr0[q] = bch2(packf2(w0 + 72 + 2 * q));
        wr1[q] = bch2(packf2(w1 + 72 + 2 * q));
    }
    // AGPR weights: pairs 76..127 (f32 elems 152..255)
    REP52(DECLA)
    REP52(INITA)

    if (t < 256) hbuf[0][t] = (_Float16)0.f;
    __syncthreads();

    float c = 0.f;
    int cur = 0;
    const _Float16* gxb = gx + (size_t)b * 512 * 1024;
    float ga = (float)gxb[r0];
    float gb = (float)gxb[r1];

    for (int step = 0; step < 512; step++) {
        const _Float16* gxn = gxb + (size_t)((step + 1) & 511) * 1024;
        _Float16 na = gxn[r0];
        _Float16 nb = gxn[r1];

        float acc0 = ga, acc1 = gb;
        const uint4* hb4 = (const uint4*)&hbuf[cur][0];  // 32 chunks of 4 pairs

        // LDS section: h chunks 0..8
        #pragma unroll
        for (int ch = 0; ch < 9; ch++) {
            uint4 u0 = wl4[ch][r0];
            uint4 u1 = wl4[ch][r1];
            uint4 hv = hb4[ch];
            acc0 = dot2f16(bch2(u0.x), bch2(hv.x), acc0);
            acc0 = dot2f16(bch2(u0.y), bch2(hv.y), acc0);
            acc0 = dot2f16(bch2(u0.z), bch2(hv.z), acc0);
            acc0 = dot2f16(bch2(u0.w), bch2(hv.w), acc0);
            acc1 = dot2f16(bch2(u1.x), bch2(hv.x), acc1);
            acc1 = dot2f16(bch2(u1.y), bch2(hv.y), acc1);
            acc1 = dot2f16(bch2(u1.z), bch2(hv.z), acc1);
            acc1 = dot2f16(bch2(u1.w), bch2(hv.w), acc1);
        }
        // AGPR section: h chunks 19..31 (reads batched, dots interleave)
        ASTEP(0, 0, 1, 2, 3)
        ASTEP(1, 4, 5, 6, 7)
        ASTEP(2, 8, 9, 10, 11)
        ASTEP(3, 12, 13, 14, 15)
        ASTEP(4, 16, 17, 18, 19)
        ASTEP(5, 20, 21, 22, 23)
        ASTEP(6, 24, 25, 26, 27)
        ASTEP(7, 28, 29, 30, 31)
        ASTEP(8, 32, 33, 34, 35)
        ASTEP(9, 36, 37, 38, 39)
        ASTEP(10, 40, 41, 42, 43)
        ASTEP(11, 44, 45, 46, 47)
        ASTEP(12, 48, 49, 50, 51)

        // ArchVGPR section: h chunks 9..18
        #pragma unroll
        for (int cc = 0; cc < 10; cc++) {
            uint4 hv = hb4[9 + cc];
            acc0 = dot2f16(wr0[4 * cc + 0], bch2(hv.x), acc0);
            acc0 = dot2f16(wr0[4 * cc + 1], bch2(hv.y), acc0);
            acc0 = dot2f16(wr0[4 * cc + 2], bch2(hv.z), acc0);
            acc0 = dot2f16(wr0[4 * cc + 3], bch2(hv.w), acc0);
            acc1 = dot2f16(wr1[4 * cc + 0], bch2(hv.x), acc1);
            acc1 = dot2f16(wr1[4 * cc + 1], bch2(hv.y), acc1);
            acc1 = dot2f16(wr1[4 * cc + 2], bch2(hv.z), acc1);
            acc1 = dot2f16(wr1[4 * cc + 3], bch2(hv.w), acc1);
        }

        if (t >= 256) {           // acc0 = f_j, acc1 = o_j for j = t-256
            xg[t - 256] = acc0;
            xg[t] = acc1;
        }
        __syncthreads();
        if (t < 256) {            // acc0 = i_j, acc1 = g_j for j = t
            float i_ = 1.f / (1.f + __expf(-acc0));
            float g_ = 1.f - 2.f / (__expf(2.f * acc1) + 1.f);
            float f_ = 1.f / (1.f + __expf(-xg[t]));
            float o_ = 1.f / (1.f + __expf(-xg[t + 256]));
            c = f_ * c + i_ * g_;
            float th = 1.f - 2.f / (__expf(2.f * c) + 1.f);
            float h = o_ * th;
            hbuf[cur ^ 1][t] = (_Float16)h;
        }
        __syncthreads();
        cur ^= 1;
        ga = (float)na;
        gb = (float)nb;
    }

    if (t < 64) {
        const float* cw = clsw + t * 256;
        float s = clsb[t];
        for (int k = 0; k < 256; k++) s += cw[k] * (float)hbuf[cur][k];
        out[b * 64 + t] = s;
    }
}

extern "C" void kernel_launch(void* const* d_in, const int* in_sizes, int n_in,
                              void* d_out, int out_size, void* d_ws, size_t ws_size,
                              hipStream_t stream) {
    const float* x    = (const float*)d_in[0];
    const float* c1w  = (const float*)d_in[1];
    const float* c1b  = (const float*)d_in[2];
    const float* c2w  = (const float*)d_in[3];
    const float* c2b  = (const float*)d_in[4];
    const float* Wih  = (const float*)d_in[5];
    const float* bih  = (const float*)d_in[6];
    const float* Whh  = (const float*)d_in[7];
    const float* bhh  = (const float*)d_in[8];
    const float* clsw = (const float*)d_in[9];
    const float* clsb = (const float*)d_in[10];

    _Float16* feat = (_Float16*)d_ws;                   // 25.2 MB
    _Float16* gx   = feat + (size_t)65536 * 192;        // 134.2 MB
    float* outp = (float*)d_out;

    hipLaunchKernelGGL(conv_kernel, dim3(16384), dim3(256), 0, stream,
                       x, c1w, c1b, c2w, c2b, feat);
    hipLaunchKernelGGL(gemm_gx_kernel, dim3(16, 1024), dim3(256), 0, stream,
                       feat, Wih, bih, bhh, gx);
    hipLaunchKernelGGL(lstm_kernel, dim3(128), dim3(512), 0, stream,
                       gx, Whh, clsw, clsb, outp);
}

// Round 9
// 1292.594 us; speedup vs baseline: 1.2061x; 1.1654x over previous
//
#include <hip/hip_runtime.h>
#include <hip/hip_bf16.h>

// GestureCNNLSTM: conv1(1->16,3x3,p1)+relu+pool2 -> conv2(16->32,3x3,p1)+relu+pool2
//  -> flatten 192 -> gx GEMM (+b_ih+b_hh) -> 512-step LSTM (H=256) -> 64-dim classifier.
// x [128][512][13][10] f32, out [128][64] f32. feat/gx f16 in ws (~159.8 MB).
//
// R8 structure: LSTM = R5's proven stream design (863us; AGPR experiments R6/R7
// regressed and are abandoned). GEMM rebuilt: prepacked f16 W, 128x128 tiles,
// swapped-operand MFMA so stores are packed 8B (was 64 scalar 2B stores/thread).

typedef _Float16 half2v __attribute__((ext_vector_type(2)));
typedef _Float16 f16x8 __attribute__((ext_vector_type(8)));
typedef float f32x4 __attribute__((ext_vector_type(4)));

__device__ __forceinline__ float dot2f16(half2v a, half2v b, float c) {
#if defined(__has_builtin)
#if __has_builtin(__builtin_amdgcn_fdot2)
    return __builtin_amdgcn_fdot2(a, b, c, false);
#else
    return c + (float)a.x * (float)b.x + (float)a.y * (float)b.y;
#endif
#else
    return c + (float)a.x * (float)b.x + (float)a.y * (float)b.y;
#endif
}

__device__ __forceinline__ unsigned int packf2(const float* p) {
    half2v hv;
    hv.x = (_Float16)p[0];
    hv.y = (_Float16)p[1];
    return __builtin_bit_cast(unsigned int, hv);
}

__device__ __forceinline__ half2v bch2(unsigned int u) {
    return __builtin_bit_cast(half2v, u);
}

__device__ __forceinline__ uint4 pack8(const float* p) {
    uint4 v;
    v.x = packf2(p + 0);
    v.y = packf2(p + 2);
    v.z = packf2(p + 4);
    v.w = packf2(p + 6);
    return v;
}

// ---------------- Kernel P1: pre-pack Wih (f32 -> f16), once ----------------
__global__ __launch_bounds__(256) void prepack_w_kernel(
    const float* __restrict__ Wih, uint4* __restrict__ wf)
{
    int idx = blockIdx.x * 256 + threadIdx.x;   // uint4 index (8 f16 each)
    if (idx < 1024 * 192 / 8) wf[idx] = pack8(Wih + idx * 8);
}

// ---------------- Kernel P2: pre-pack W_hh stream section (R5) ----------------
// sw[c][r] (c=0..12, r=0..1023) = pairs 76+4c..76+4c+3 of row r
__global__ __launch_bounds__(256) void prepack_sw_kernel(
    const float* __restrict__ Whh, uint4* __restrict__ sw)
{
    int idx = blockIdx.x * 256 + threadIdx.x;
    if (idx < 13 * 1024) {
        int c = idx >> 10, r = idx & 1023;
        sw[idx] = pack8(Whh + (size_t)r * 256 + 152 + 8 * c);
    }
}

// ---------------- Kernel A: fused conv1+pool1+conv2+pool2 ----------------
__global__ __launch_bounds__(256) void conv_kernel(
    const float* __restrict__ x,     // [65536][13][10]
    const float* __restrict__ c1w,   // [16][1][3][3]
    const float* __restrict__ c1b,   // [16]
    const float* __restrict__ c2w,   // [32][16][3][3]
    const float* __restrict__ c2b,   // [32]
    _Float16* __restrict__ feat)     // [65536][192]
{
    __shared__ float w1t[9 * 16];
    __shared__ float b1s[16];
    __shared__ float w2t[16 * 9 * 32];
    __shared__ float b2s[32];
    __shared__ float xp[4][14 * 12];
    __shared__ float p1p[4][16 * 8 * 7];

    const int tid = threadIdx.x;

    for (int idx = tid; idx < 144; idx += 256) {
        int oc = idx / 9, k = idx % 9;
        w1t[k * 16 + oc] = c1w[idx];
    }
    if (tid < 16) b1s[tid] = c1b[tid];
    for (int idx = tid; idx < 4608; idx += 256) {
        int oc = idx / 144, ic = (idx / 9) % 16, k = idx % 9;
        w2t[(ic * 9 + k) * 32 + oc] = c2w[idx];
    }
    if (tid < 32) b2s[tid] = c2b[tid];

    const int w = tid >> 6;
    const int lane = tid & 63;
    const int img = blockIdx.x * 4 + w;

    for (int i = lane; i < 14 * 12; i += 64) xp[w][i] = 0.f;
    for (int i = lane; i < 16 * 8 * 7; i += 64) p1p[w][i] = 0.f;
    __syncthreads();

    const float* xin = x + (size_t)img * 130;
    for (int i = lane; i < 130; i += 64) {
        int r = i / 10, c = i % 10;
        xp[w][(r + 1) * 12 + (c + 1)] = xin[i];
    }
    __syncthreads();

    {
        const int oc = lane & 15, q = lane >> 4;
        #pragma unroll
        for (int i = 0; i < 8; i++) {
            int pos = i * 4 + q;
            if (pos < 30) {
                int ph = pos / 5, pw = pos % 5;
                float cmax = -1e30f;
                #pragma unroll
                for (int pt = 0; pt < 4; pt++) {
                    int Y = 2 * ph + (pt >> 1), X = 2 * pw + (pt & 1);
                    float s = 0.f;
                    #pragma unroll
                    for (int k = 0; k < 9; k++) {
                        int dy = k / 3, dx = k % 3;
                        s += w1t[k * 16 + oc] * xp[w][(Y + dy) * 12 + X + dx];
                    }
                    cmax = fmaxf(cmax, s);
                }
                p1p[w][(oc * 8 + ph + 1) * 7 + (pw + 1)] = fmaxf(0.f, cmax + b1s[oc]);
            }
        }
    }
    __syncthreads();

    {
        const int oc = lane & 31, pw2 = lane >> 5;
        float acc[3][4];
        #pragma unroll
        for (int a = 0; a < 3; a++)
            #pragma unroll
            for (int b = 0; b < 4; b++) acc[a][b] = 0.f;

        for (int ic = 0; ic < 16; ic++) {
            #pragma unroll
            for (int k = 0; k < 9; k++) {
                int dy = k / 3, dx = k % 3;
                float wv = w2t[(ic * 9 + k) * 32 + oc];
                #pragma unroll
                for (int ph2 = 0; ph2 < 3; ph2++) {
                    #pragma unroll
                    for (int pt = 0; pt < 4; pt++) {
                        int y = 2 * ph2 + (pt >> 1) + dy;
                        int xx = 2 * pw2 + (pt & 1) + dx;
                        acc[ph2][pt] += wv * p1p[w][(ic * 8 + y) * 7 + xx];
                    }
                }
            }
        }
        float bias = b2s[oc];
        _Float16* fo = feat + (size_t)img * 192;
        #pragma unroll
        for (int ph2 = 0; ph2 < 3; ph2++) {
            float m = fmaxf(fmaxf(acc[ph2][0], acc[ph2][1]),
                            fmaxf(acc[ph2][2], acc[ph2][3]));
            fo[oc * 6 + ph2 * 2 + pw2] = (_Float16)fmaxf(0.f, m + bias);
        }
    }
}

// ---------------- Kernel B: gx = feat @ W_ih^T + bias via MFMA f16 ----------
// 128m x 128n tiles, grid (8 n, 512 m), 256 thr (4 waves). Wave w owns n-rows
// [w*32, w*32+32). Swapped operands: acc = mfma(Wfrag, featfrag) -> D row
// indexes n (4 consecutive per thread), col indexes m -> packed 8B stores.
__global__ __launch_bounds__(256, 1) void gemm_gx_kernel(
    const _Float16* __restrict__ feat,  // [65536][192]
    const _Float16* __restrict__ wf16,  // [1024][192] (prepacked)
    const float* __restrict__ bih,
    const float* __restrict__ bhh,
    _Float16* __restrict__ gx)          // [65536][1024]
{
    __shared__ uint4 As4[128][25];   // feat tile, 51.2 KB (row stride 400 B)
    __shared__ uint4 Ws4[128][25];   // W tile, 51.2 KB

    const int tid = threadIdx.x;
    const int n0 = blockIdx.x * 128;
    const int m0 = blockIdx.y * 128;

    #pragma unroll
    for (int it = 0; it < 12; it++) {
        int q = tid + it * 256;          // 0..3071
        int r = q / 24, c = q % 24;
        As4[r][c] = *(const uint4*)(feat + (size_t)(m0 + r) * 192 + c * 8);
        Ws4[r][c] = *(const uint4*)(wf16 + (size_t)(n0 + r) * 192 + c * 8);
    }
    __syncthreads();

    const int w = tid >> 6;
    const int lane = tid & 63;
    const int lm = lane & 15;
    const int lk = lane >> 4;

    f32x4 acc[2][8] = {};
    #pragma unroll
    for (int ks = 0; ks < 6; ks++) {
        f16x8 wf[2], af[8];
        #pragma unroll
        for (int nf = 0; nf < 2; nf++)
            wf[nf] = __builtin_bit_cast(f16x8, Ws4[w * 32 + nf * 16 + lm][ks * 4 + lk]);
        #pragma unroll
        for (int mf = 0; mf < 8; mf++)
            af[mf] = __builtin_bit_cast(f16x8, As4[mf * 16 + lm][ks * 4 + lk]);
        #pragma unroll
        for (int nf = 0; nf < 2; nf++)
            #pragma unroll
            for (int mf = 0; mf < 8; mf++)
                acc[nf][mf] = __builtin_amdgcn_mfma_f32_16x16x32_f16(
                    wf[nf], af[mf], acc[nf][mf], 0, 0, 0);
    }

    #pragma unroll
    for (int nf = 0; nf < 2; nf++) {
        int nb = n0 + w * 32 + nf * 16 + lk * 4;   // 4 consecutive n
        float4 b1 = *(const float4*)&bih[nb];
        float4 b2 = *(const float4*)&bhh[nb];
        float bs0 = b1.x + b2.x, bs1 = b1.y + b2.y;
        float bs2 = b1.z + b2.z, bs3 = b1.w + b2.w;
        #pragma unroll
        for (int mf = 0; mf < 8; mf++) {
            int m = m0 + mf * 16 + lm;
            union { _Float16 h[4]; uint2 u; } pk;
            pk.h[0] = (_Float16)(acc[nf][mf][0] + bs0);
            pk.h[1] = (_Float16)(acc[nf][mf][1] + bs1);
            pk.h[2] = (_Float16)(acc[nf][mf][2] + bs2);
            pk.h[3] = (_Float16)(acc[nf][mf][3] + bs3);
            *(uint2*)&gx[(size_t)m * 1024 + nb] = pk.u;
        }
    }
}

// ---------------- Kernel C: 512-step LSTM + classifier (R5 structure) --------
// 128 blocks x 512 threads (8 waves, 2/SIMD). Thread t owns rows r0=t, r1=t+512.
// Per row: pairs 0..35 LDS (144 KB) | 36..75 ArchVGPR (80 regs) | 76..127
// streamed from pre-packed sw (uint4 [13][1024], coalesced, L2-hot).
__global__ __launch_bounds__(512, 2) void lstm_kernel(
    const _Float16* __restrict__ gx, // [128][512][1024]
    const float* __restrict__ Whh,   // [1024][256]
    const uint4* __restrict__ sw,    // [13][1024]
    const float* __restrict__ clsw,  // [64][256]
    const float* __restrict__ clsb,  // [64]
    float* __restrict__ out)         // [128][64]
{
    __shared__ uint4 wl4[9][1024];                     // 144 KB
    __shared__ __align__(16) _Float16 hbuf[2][256];    // 1 KB
    __shared__ float xg[512];                          // 2 KB

    const int t = threadIdx.x;
    const int b = blockIdx.x;
    const int r0 = t, r1 = t + 512;

    const float* w0 = Whh + (size_t)r0 * 256;
    const float* w1 = Whh + (size_t)r1 * 256;

    // LDS weights: pairs 0..35 (f32 elems 0..71)
    #pragma unroll
    for (int ch = 0; ch < 9; ch++) {
        wl4[ch][r0] = pack8(w0 + 8 * ch);
        wl4[ch][r1] = pack8(w1 + 8 * ch);
    }
    // register weights: pairs 36..75 (f32 elems 72..151)
    half2v wr0[40], wr1[40];
    #pragma unroll
    for (int q = 0; q < 40; q++) {
        wr0[q] = bch2(packf2(w0 + 72 + 2 * q));
        wr1[q] = bch2(packf2(w1 + 72 + 2 * q));
    }
    if (t < 256) hbuf[0][t] = (_Float16)0.f;
    __syncthreads();

    float c = 0.f;
    int cur = 0;
    const _Float16* gxb = gx + (size_t)b * 512 * 1024;
    float ga = (float)gxb[r0];
    float gb = (float)gxb[r1];

    for (int step = 0; step < 512; step++) {
        const _Float16* gxn = gxb + (size_t)((step + 1) & 511) * 1024;
        _Float16 na = gxn[r0];
        _Float16 nb = gxn[r1];

        float acc0 = ga, acc1 = gb;
        const uint4* hb4 = (const uint4*)&hbuf[cur][0];  // 32 chunks of 4 pairs

        // STREAM section first: issue global loads early, consume as they land.
        #pragma unroll
        for (int sc = 0; sc < 13; sc++) {
            uint4 u0 = sw[sc * 1024 + r0];
            uint4 u1 = sw[sc * 1024 + r1];
            uint4 hv = hb4[19 + sc];
            acc0 = dot2f16(bch2(u0.x), bch2(hv.x), acc0);
            acc0 = dot2f16(bch2(u0.y), bch2(hv.y), acc0);
            acc0 = dot2f16(bch2(u0.z), bch2(hv.z), acc0);
            acc0 = dot2f16(bch2(u0.w), bch2(hv.w), acc0);
            acc1 = dot2f16(bch2(u1.x), bch2(hv.x), acc1);
            acc1 = dot2f16(bch2(u1.y), bch2(hv.y), acc1);
            acc1 = dot2f16(bch2(u1.z), bch2(hv.z), acc1);
            acc1 = dot2f16(bch2(u1.w), bch2(hv.w), acc1);
        }
        // LDS section: chunks 0..8
        #pragma unroll
        for (int ch = 0; ch < 9; ch++) {
            uint4 u0 = wl4[ch][r0];
            uint4 u1 = wl4[ch][r1];
            uint4 hv = hb4[ch];
            acc0 = dot2f16(bch2(u0.x), bch2(hv.x), acc0);
            acc0 = dot2f16(bch2(u0.y), bch2(hv.y), acc0);
            acc0 = dot2f16(bch2(u0.z), bch2(hv.z), acc0);
            acc0 = dot2f16(bch2(u0.w), bch2(hv.w), acc0);
            acc1 = dot2f16(bch2(u1.x), bch2(hv.x), acc1);
            acc1 = dot2f16(bch2(u1.y), bch2(hv.y), acc1);
            acc1 = dot2f16(bch2(u1.z), bch2(hv.z), acc1);
            acc1 = dot2f16(bch2(u1.w), bch2(hv.w), acc1);
        }
        // REG section: chunks 9..18
        #pragma unroll
        for (int cc = 0; cc < 10; cc++) {
            uint4 hv = hb4[9 + cc];
            acc0 = dot2f16(wr0[4 * cc + 0], bch2(hv.x), acc0);
            acc0 = dot2f16(wr0[4 * cc + 1], bch2(hv.y), acc0);
            acc0 = dot2f16(wr0[4 * cc + 2], bch2(hv.z), acc0);
            acc0 = dot2f16(wr0[4 * cc + 3], bch2(hv.w), acc0);
            acc1 = dot2f16(wr1[4 * cc + 0], bch2(hv.x), acc1);
            acc1 = dot2f16(wr1[4 * cc + 1], bch2(hv.y), acc1);
            acc1 = dot2f16(wr1[4 * cc + 2], bch2(hv.z), acc1);
            acc1 = dot2f16(wr1[4 * cc + 3], bch2(hv.w), acc1);
        }

        if (t >= 256) {           // acc0 = f_j, acc1 = o_j for j = t-256
            xg[t - 256] = acc0;
            xg[t] = acc1;
        }
        __syncthreads();
        if (t < 256) {            // acc0 = i_j, acc1 = g_j for j = t
            float i_ = 1.f / (1.f + __expf(-acc0));
            float g_ = 1.f - 2.f / (__expf(2.f * acc1) + 1.f);
            float f_ = 1.f / (1.f + __expf(-xg[t]));
            float o_ = 1.f / (1.f + __expf(-xg[t + 256]));
            c = f_ * c + i_ * g_;
            float th = 1.f - 2.f / (__expf(2.f * c) + 1.f);
            float h = o_ * th;
            hbuf[cur ^ 1][t] = (_Float16)h;
        }
        __syncthreads();
        cur ^= 1;
        ga = (float)na;
        gb = (float)nb;
    }

    if (t < 64) {
        const float* cw = clsw + t * 256;
        float s = clsb[t];
        for (int k = 0; k < 256; k++) s += cw[k] * (float)hbuf[cur][k];
        out[b * 64 + t] = s;
    }
}

extern "C" void kernel_launch(void* const* d_in, const int* in_sizes, int n_in,
                              void* d_out, int out_size, void* d_ws, size_t ws_size,
                              hipStream_t stream) {
    const float* x    = (const float*)d_in[0];
    const float* c1w  = (const float*)d_in[1];
    const float* c1b  = (const float*)d_in[2];
    const float* c2w  = (const float*)d_in[3];
    const float* c2b  = (const float*)d_in[4];
    const float* Wih  = (const float*)d_in[5];
    const float* bih  = (const float*)d_in[6];
    const float* Whh  = (const float*)d_in[7];
    const float* bhh  = (const float*)d_in[8];
    const float* clsw = (const float*)d_in[9];
    const float* clsb = (const float*)d_in[10];

    _Float16* feat = (_Float16*)d_ws;                     // 25.2 MB
    _Float16* gx   = feat + (size_t)65536 * 192;          // 134.2 MB
    uint4* aux     = (uint4*)(gx + (size_t)65536 * 1024); // 384 KB union:
    // aux serves as wf16 (prepack_w -> gemm), then is overwritten as sw
    // (prepack_sw after gemm -> lstm). Sequential stream => no overlap hazard.
    float* outp = (float*)d_out;

    hipLaunchKernelGGL(prepack_w_kernel, dim3(96), dim3(256), 0, stream, Wih, aux);
    hipLaunchKernelGGL(conv_kernel, dim3(16384), dim3(256), 0, stream,
                       x, c1w, c1b, c2w, c2b, feat);
    hipLaunchKernelGGL(gemm_gx_kernel, dim3(8, 512), dim3(256), 0, stream,
                       feat, (const _Float16*)aux, bih, bhh, gx);
    hipLaunchKernelGGL(prepack_sw_kernel, dim3(52), dim3(256), 0, stream, Whh, aux);
    hipLaunchKernelGGL(lstm_kernel, dim3(128), dim3(512), 0, stream,
                       gx, Whh, aux, clsw, clsb, outp);
}

// Round 10
// 1105.080 us; speedup vs baseline: 1.4107x; 1.1697x over previous
//
#include <hip/hip_runtime.h>
#include <hip/hip_bf16.h>

// GestureCNNLSTM: conv1(1->16,3x3,p1)+relu+pool2 -> conv2(16->32,3x3,p1)+relu+pool2
//  -> flatten 192 -> gx GEMM (+b_ih+b_hh) -> 512-step LSTM (H=256) -> 64-dim classifier.
// x [128][512][13][10] f32, out [128][64] f32. feat/gx f16 in ws (~159.8 MB).
//
// R9: conv phase-2 rebuilt as f16 ic-pair dot2 with register im2col (halves the
// instruction stream). LSTM = R5 structure with residency nudged: 38 pairs LDS
// (+wl2), 42 pairs regs, 48 pairs streamed (was 36/40/52) -> -7.7% L2 stream.

typedef _Float16 half2v __attribute__((ext_vector_type(2)));
typedef _Float16 f16x8 __attribute__((ext_vector_type(8)));
typedef float f32x4 __attribute__((ext_vector_type(4)));

__device__ __forceinline__ float dot2f16(half2v a, half2v b, float c) {
#if defined(__has_builtin)
#if __has_builtin(__builtin_amdgcn_fdot2)
    return __builtin_amdgcn_fdot2(a, b, c, false);
#else
    return c + (float)a.x * (float)b.x + (float)a.y * (float)b.y;
#endif
#else
    return c + (float)a.x * (float)b.x + (float)a.y * (float)b.y;
#endif
}

__device__ __forceinline__ float dot2u(unsigned int a, unsigned int b, float c) {
    return dot2f16(__builtin_bit_cast(half2v, a), __builtin_bit_cast(half2v, b), c);
}

__device__ __forceinline__ unsigned int packf2(const float* p) {
    half2v hv;
    hv.x = (_Float16)p[0];
    hv.y = (_Float16)p[1];
    return __builtin_bit_cast(unsigned int, hv);
}

__device__ __forceinline__ unsigned int packff(float a, float b) {
    half2v hv;
    hv.x = (_Float16)a;
    hv.y = (_Float16)b;
    return __builtin_bit_cast(unsigned int, hv);
}

__device__ __forceinline__ half2v bch2(unsigned int u) {
    return __builtin_bit_cast(half2v, u);
}

__device__ __forceinline__ uint4 pack8(const float* p) {
    uint4 v;
    v.x = packf2(p + 0);
    v.y = packf2(p + 2);
    v.z = packf2(p + 4);
    v.w = packf2(p + 6);
    return v;
}

// ---------------- Kernel P1: pre-pack Wih (f32 -> f16), once ----------------
__global__ __launch_bounds__(256) void prepack_w_kernel(
    const float* __restrict__ Wih, uint4* __restrict__ wf)
{
    int idx = blockIdx.x * 256 + threadIdx.x;   // uint4 index (8 f16 each)
    if (idx < 1024 * 192 / 8) wf[idx] = pack8(Wih + idx * 8);
}

// ---------------- Kernel P2: pre-pack W_hh stream section ----------------
// sw[c][r] (c=0..11, r=0..1023) = pairs 80+4c..80+4c+3 of row r (f32 elems 160+8c..)
__global__ __launch_bounds__(256) void prepack_sw_kernel(
    const float* __restrict__ Whh, uint4* __restrict__ sw)
{
    int idx = blockIdx.x * 256 + threadIdx.x;
    if (idx < 12 * 1024) {
        int c = idx >> 10, r = idx & 1023;
        sw[idx] = pack8(Whh + (size_t)r * 256 + 160 + 8 * c);
    }
}

// ---------------- Kernel A: fused conv1+pool1+conv2+pool2 ----------------
// Phase 2 in f16 ic-pair dot2: pool1 stored [pos][oc] f16 (ic pairs adjacent),
// weights [icp][k][oc] uint pairs; per icp the lane preloads its 8x4 window
// into 32 regs (broadcast LDS reads) then runs 108 read-free dot2.
__global__ __launch_bounds__(256) void conv_kernel(
    const float* __restrict__ x,     // [65536][13][10]
    const float* __restrict__ c1w,   // [16][1][3][3]
    const float* __restrict__ c1b,   // [16]
    const float* __restrict__ c2w,   // [32][16][3][3]
    const float* __restrict__ c2b,   // [32]
    _Float16* __restrict__ feat)     // [65536][192]
{
    __shared__ float w1t[9 * 16];
    __shared__ float b1s[16];
    __shared__ unsigned int w2h[8 * 9 * 32];   // [icp][k][oc], 9.2 KB
    __shared__ float b2s[32];
    __shared__ float xp[4][14 * 12];
    __shared__ __align__(4) _Float16 p1ph[4][8 * 7 * 16];  // [y*7+x][oc], 7 KB

    const int tid = threadIdx.x;

    for (int idx = tid; idx < 144; idx += 256) {
        int oc = idx / 9, k = idx % 9;
        w1t[k * 16 + oc] = c1w[idx];
    }
    if (tid < 16) b1s[tid] = c1b[tid];
    // w2h[icp][k][oc] = pack(c2w[oc][2icp][k], c2w[oc][2icp+1][k])
    for (int idx = tid; idx < 2304; idx += 256) {
        int icp = idx / 288, rem = idx % 288;
        int k = rem / 32, oc = rem % 32;
        float a = c2w[oc * 144 + (2 * icp) * 9 + k];
        float b = c2w[oc * 144 + (2 * icp + 1) * 9 + k];
        w2h[idx] = packff(a, b);
    }
    if (tid < 32) b2s[tid] = c2b[tid];

    const int w = tid >> 6;
    const int lane = tid & 63;
    const int img = blockIdx.x * 4 + w;

    for (int i = lane; i < 14 * 12; i += 64) xp[w][i] = 0.f;
    for (int i = lane; i < 8 * 7 * 16; i += 64) p1ph[w][i] = (_Float16)0.f;
    __syncthreads();

    const float* xin = x + (size_t)img * 130;
    for (int i = lane; i < 130; i += 64) {
        int r = i / 10, c = i % 10;
        xp[w][(r + 1) * 12 + (c + 1)] = xin[i];
    }
    __syncthreads();

    // phase 1: conv1+relu+pool -> p1ph interior (f16, [pos][oc])
    {
        const int oc = lane & 15, q = lane >> 4;
        #pragma unroll
        for (int i = 0; i < 8; i++) {
            int pos = i * 4 + q;
            if (pos < 30) {
                int ph = pos / 5, pw = pos % 5;
                float cmax = -1e30f;
                #pragma unroll
                for (int pt = 0; pt < 4; pt++) {
                    int Y = 2 * ph + (pt >> 1), X = 2 * pw + (pt & 1);
                    float s = 0.f;
                    #pragma unroll
                    for (int k = 0; k < 9; k++) {
                        int dy = k / 3, dx = k % 3;
                        s += w1t[k * 16 + oc] * xp[w][(Y + dy) * 12 + X + dx];
                    }
                    cmax = fmaxf(cmax, s);
                }
                p1ph[w][((ph + 1) * 7 + (pw + 1)) * 16 + oc] =
                    (_Float16)fmaxf(0.f, cmax + b1s[oc]);
            }
        }
    }
    __syncthreads();

    // phase 2: conv2+relu+pool via dot2, register im2col
    {
        const int oc = lane & 31, pw2 = lane >> 5;
        float acc[3][4] = {};
        const _Float16* P = &p1ph[w][0];

        #pragma unroll
        for (int icp = 0; icp < 8; icp++) {
            unsigned int hreg[32];
            #pragma unroll
            for (int y = 0; y < 8; y++)
                #pragma unroll
                for (int xx = 0; xx < 4; xx++) {
                    int xcol = 2 * pw2 + xx;
                    hreg[y * 4 + xx] =
                        *(const unsigned int*)&P[(y * 7 + xcol) * 16 + 2 * icp];
                }
            #pragma unroll
            for (int k = 0; k < 9; k++) {
                int dy = k / 3, dx = k % 3;
                unsigned int wv = w2h[(icp * 9 + k) * 32 + oc];
                #pragma unroll
                for (int ph2 = 0; ph2 < 3; ph2++) {
                    #pragma unroll
                    for (int pt = 0; pt < 4; pt++) {
                        int y = 2 * ph2 + (pt >> 1) + dy;
                        int xx2 = (pt & 1) + dx;
                        acc[ph2][pt] = dot2u(wv, hreg[y * 4 + xx2], acc[ph2][pt]);
                    }
                }
            }
        }
        float bias = b2s[oc];
        _Float16* fo = feat + (size_t)img * 192;
        #pragma unroll
        for (int ph2 = 0; ph2 < 3; ph2++) {
            float m = fmaxf(fmaxf(acc[ph2][0], acc[ph2][1]),
                            fmaxf(acc[ph2][2], acc[ph2][3]));
            fo[oc * 6 + ph2 * 2 + pw2] = (_Float16)fmaxf(0.f, m + bias);
        }
    }
}

// ---------------- Kernel B: gx = feat @ W_ih^T + bias via MFMA f16 ----------
__global__ __launch_bounds__(256, 1) void gemm_gx_kernel(
    const _Float16* __restrict__ feat,  // [65536][192]
    const _Float16* __restrict__ wf16,  // [1024][192] (prepacked)
    const float* __restrict__ bih,
    const float* __restrict__ bhh,
    _Float16* __restrict__ gx)          // [65536][1024]
{
    __shared__ uint4 As4[128][25];
    __shared__ uint4 Ws4[128][25];

    const int tid = threadIdx.x;
    const int n0 = blockIdx.x * 128;
    const int m0 = blockIdx.y * 128;

    #pragma unroll
    for (int it = 0; it < 12; it++) {
        int q = tid + it * 256;
        int r = q / 24, c = q % 24;
        As4[r][c] = *(const uint4*)(feat + (size_t)(m0 + r) * 192 + c * 8);
        Ws4[r][c] = *(const uint4*)(wf16 + (size_t)(n0 + r) * 192 + c * 8);
    }
    __syncthreads();

    const int w = tid >> 6;
    const int lane = tid & 63;
    const int lm = lane & 15;
    const int lk = lane >> 4;

    f32x4 acc[2][8] = {};
    #pragma unroll
    for (int ks = 0; ks < 6; ks++) {
        f16x8 wf[2], af[8];
        #pragma unroll
        for (int nf = 0; nf < 2; nf++)
            wf[nf] = __builtin_bit_cast(f16x8, Ws4[w * 32 + nf * 16 + lm][ks * 4 + lk]);
        #pragma unroll
        for (int mf = 0; mf < 8; mf++)
            af[mf] = __builtin_bit_cast(f16x8, As4[mf * 16 + lm][ks * 4 + lk]);
        #pragma unroll
        for (int nf = 0; nf < 2; nf++)
            #pragma unroll
            for (int mf = 0; mf < 8; mf++)
                acc[nf][mf] = __builtin_amdgcn_mfma_f32_16x16x32_f16(
                    wf[nf], af[mf], acc[nf][mf], 0, 0, 0);
    }

    #pragma unroll
    for (int nf = 0; nf < 2; nf++) {
        int nb = n0 + w * 32 + nf * 16 + lk * 4;
        float4 b1 = *(const float4*)&bih[nb];
        float4 b2 = *(const float4*)&bhh[nb];
        float bs0 = b1.x + b2.x, bs1 = b1.y + b2.y;
        float bs2 = b1.z + b2.z, bs3 = b1.w + b2.w;
        #pragma unroll
        for (int mf = 0; mf < 8; mf++) {
            int m = m0 + mf * 16 + lm;
            union { _Float16 h[4]; uint2 u; } pk;
            pk.h[0] = (_Float16)(acc[nf][mf][0] + bs0);
            pk.h[1] = (_Float16)(acc[nf][mf][1] + bs1);
            pk.h[2] = (_Float16)(acc[nf][mf][2] + bs2);
            pk.h[3] = (_Float16)(acc[nf][mf][3] + bs3);
            *(uint2*)&gx[(size_t)m * 1024 + nb] = pk.u;
        }
    }
}

// ---------------- Kernel C: 512-step LSTM + classifier ----------------
// 128 blocks x 512 threads (8 waves, 2/SIMD). Thread t owns rows r0=t, r1=t+512.
// Per row (128 f16 pairs): 0..35 wl4 LDS | 36..37 wl2 LDS | 38..79 regs (42) |
// 80..127 streamed from sw (12 uint4 chunks, L2-hot).
__global__ __launch_bounds__(512, 2) void lstm_kernel(
    const _Float16* __restrict__ gx, // [128][512][1024]
    const float* __restrict__ Whh,   // [1024][256]
    const uint4* __restrict__ sw,    // [12][1024]
    const float* __restrict__ clsw,  // [64][256]
    const float* __restrict__ clsb,  // [64]
    float* __restrict__ out)         // [128][64]
{
    __shared__ uint4 wl4[9][1024];                     // 144 KB: pairs 0..35
    __shared__ uint2 wl2[1024];                        // 8 KB: pairs 36..37
    __shared__ __align__(16) _Float16 hbuf[2][256];    // 1 KB
    __shared__ float xg[512];                          // 2 KB

    const int t = threadIdx.x;
    const int b = blockIdx.x;
    const int r0 = t, r1 = t + 512;

    const float* w0 = Whh + (size_t)r0 * 256;
    const float* w1 = Whh + (size_t)r1 * 256;

    #pragma unroll
    for (int ch = 0; ch < 9; ch++) {
        wl4[ch][r0] = pack8(w0 + 8 * ch);
        wl4[ch][r1] = pack8(w1 + 8 * ch);
    }
    {
        uint2 v0, v1;
        v0.x = packf2(w0 + 72); v0.y = packf2(w0 + 74);
        v1.x = packf2(w1 + 72); v1.y = packf2(w1 + 74);
        wl2[r0] = v0;
        wl2[r1] = v1;
    }
    // register weights: pairs 38..79 (f32 elems 76..159)
    half2v wr0[42], wr1[42];
    #pragma unroll
    for (int q = 0; q < 42; q++) {
        wr0[q] = bch2(packf2(w0 + 76 + 2 * q));
        wr1[q] = bch2(packf2(w1 + 76 + 2 * q));
    }
    if (t < 256) hbuf[0][t] = (_Float16)0.f;
    __syncthreads();

    float c = 0.f;
    int cur = 0;
    const _Float16* gxb = gx + (size_t)b * 512 * 1024;
    float ga = (float)gxb[r0];
    float gb = (float)gxb[r1];

    for (int step = 0; step < 512; step++) {
        const _Float16* gxn = gxb + (size_t)((step + 1) & 511) * 1024;
        _Float16 na = gxn[r0];
        _Float16 nb = gxn[r1];

        float acc0 = ga, acc1 = gb;
        const uint4* hb4 = (const uint4*)&hbuf[cur][0];  // 32 chunks of 4 pairs

        // STREAM section: h chunks 20..31 <-> sw chunks 0..11
        #pragma unroll
        for (int sc = 0; sc < 12; sc++) {
            uint4 u0 = sw[sc * 1024 + r0];
            uint4 u1 = sw[sc * 1024 + r1];
            uint4 hv = hb4[20 + sc];
            acc0 = dot2f16(bch2(u0.x), bch2(hv.x), acc0);
            acc0 = dot2f16(bch2(u0.y), bch2(hv.y), acc0);
            acc0 = dot2f16(bch2(u0.z), bch2(hv.z), acc0);
            acc0 = dot2f16(bch2(u0.w), bch2(hv.w), acc0);
            acc1 = dot2f16(bch2(u1.x), bch2(hv.x), acc1);
            acc1 = dot2f16(bch2(u1.y), bch2(hv.y), acc1);
            acc1 = dot2f16(bch2(u1.z), bch2(hv.z), acc1);
            acc1 = dot2f16(bch2(u1.w), bch2(hv.w), acc1);
        }
        // LDS wl4: h chunks 0..8
        #pragma unroll
        for (int ch = 0; ch < 9; ch++) {
            uint4 u0 = wl4[ch][r0];
            uint4 u1 = wl4[ch][r1];
            uint4 hv = hb4[ch];
            acc0 = dot2f16(bch2(u0.x), bch2(hv.x), acc0);
            acc0 = dot2f16(bch2(u0.y), bch2(hv.y), acc0);
            acc0 = dot2f16(bch2(u0.z), bch2(hv.z), acc0);
            acc0 = dot2f16(bch2(u0.w), bch2(hv.w), acc0);
            acc1 = dot2f16(bch2(u1.x), bch2(hv.x), acc1);
            acc1 = dot2f16(bch2(u1.y), bch2(hv.y), acc1);
            acc1 = dot2f16(bch2(u1.z), bch2(hv.z), acc1);
            acc1 = dot2f16(bch2(u1.w), bch2(hv.w), acc1);
        }
        // LDS wl2 (pairs 36,37) + regs (pairs 38,39) use h chunk 9
        {
            uint4 hv = hb4[9];
            uint2 u0 = wl2[r0];
            uint2 u1 = wl2[r1];
            acc0 = dot2f16(bch2(u0.x), bch2(hv.x), acc0);
            acc0 = dot2f16(bch2(u0.y), bch2(hv.y), acc0);
            acc1 = dot2f16(bch2(u1.x), bch2(hv.x), acc1);
            acc1 = dot2f16(bch2(u1.y), bch2(hv.y), acc1);
            acc0 = dot2f16(wr0[0], bch2(hv.z), acc0);
            acc0 = dot2f16(wr0[1], bch2(hv.w), acc0);
            acc1 = dot2f16(wr1[0], bch2(hv.z), acc1);
            acc1 = dot2f16(wr1[1], bch2(hv.w), acc1);
        }
        // REG section: h chunks 10..19, wr 2..41
        #pragma unroll
        for (int cc = 0; cc < 10; cc++) {
            uint4 hv = hb4[10 + cc];
            acc0 = dot2f16(wr0[2 + 4 * cc + 0], bch2(hv.x), acc0);
            acc0 = dot2f16(wr0[2 + 4 * cc + 1], bch2(hv.y), acc0);
            acc0 = dot2f16(wr0[2 + 4 * cc + 2], bch2(hv.z), acc0);
            acc0 = dot2f16(wr0[2 + 4 * cc + 3], bch2(hv.w), acc0);
            acc1 = dot2f16(wr1[2 + 4 * cc + 0], bch2(hv.x), acc1);
            acc1 = dot2f16(wr1[2 + 4 * cc + 1], bch2(hv.y), acc1);
            acc1 = dot2f16(wr1[2 + 4 * cc + 2], bch2(hv.z), acc1);
            acc1 = dot2f16(wr1[2 + 4 * cc + 3], bch2(hv.w), acc1);
        }

        if (t >= 256) {           // acc0 = f_j, acc1 = o_j for j = t-256
            xg[t - 256] = acc0;
            xg[t] = acc1;
        }
        __syncthreads();
        if (t < 256) {            // acc0 = i_j, acc1 = g_j for j = t
            float i_ = 1.f / (1.f + __expf(-acc0));
            float g_ = 1.f - 2.f / (__expf(2.f * acc1) + 1.f);
            float f_ = 1.f / (1.f + __expf(-xg[t]));
            float o_ = 1.f / (1.f + __expf(-xg[t + 256]));
            c = f_ * c + i_ * g_;
            float th = 1.f - 2.f / (__expf(2.f * c) + 1.f);
            float h = o_ * th;
            hbuf[cur ^ 1][t] = (_Float16)h;
        }
        __syncthreads();
        cur ^= 1;
        ga = (float)na;
        gb = (float)nb;
    }

    if (t < 64) {
        const float* cw = clsw + t * 256;
        float s = clsb[t];
        for (int k = 0; k < 256; k++) s += cw[k] * (float)hbuf[cur][k];
        out[b * 64 + t] = s;
    }
}

extern "C" void kernel_launch(void* const* d_in, const int* in_sizes, int n_in,
                              void* d_out, int out_size, void* d_ws, size_t ws_size,
                              hipStream_t stream) {
    const float* x    = (const float*)d_in[0];
    const float* c1w  = (const float*)d_in[1];
    const float* c1b  = (const float*)d_in[2];
    const float* c2w  = (const float*)d_in[3];
    const float* c2b  = (const float*)d_in[4];
    const float* Wih  = (const float*)d_in[5];
    const float* bih  = (const float*)d_in[6];
    const float* Whh  = (const float*)d_in[7];
    const float* bhh  = (const float*)d_in[8];
    const float* clsw = (const float*)d_in[9];
    const float* clsb = (const float*)d_in[10];

    _Float16* feat = (_Float16*)d_ws;                     // 25.2 MB
    _Float16* gx   = feat + (size_t)65536 * 192;          // 134.2 MB
    uint4* aux     = (uint4*)(gx + (size_t)65536 * 1024); // 384 KB union:
    // aux = wf16 for gemm, then overwritten as sw for lstm (sequential stream).
    float* outp = (float*)d_out;

    hipLaunchKernelGGL(prepack_w_kernel, dim3(96), dim3(256), 0, stream, Wih, aux);
    hipLaunchKernelGGL(conv_kernel, dim3(16384), dim3(256), 0, stream,
                       x, c1w, c1b, c2w, c2b, feat);
    hipLaunchKernelGGL(gemm_gx_kernel, dim3(8, 512), dim3(256), 0, stream,
                       feat, (const _Float16*)aux, bih, bhh, gx);
    hipLaunchKernelGGL(prepack_sw_kernel, dim3(48), dim3(256), 0, stream, Whh, aux);
    hipLaunchKernelGGL(lstm_kernel, dim3(128), dim3(512), 0, stream,
                       gx, Whh, aux, clsw, clsb, outp);
}